// Round 11
// baseline (282.414 us; speedup 1.0000x reference)
//
#include <hip/hip_runtime.h>

#define NN 12800
#define NE 204800

// ---------------- static device scratch (~14.5 MB) ----------------
__device__ __align__(16) float g_outA[NN * 16];  // node features ping
__device__ __align__(16) float g_outB[NN * 16];  // node features pong
__device__ __align__(16) float g_ehs[NE * 16];   // edge hidden, DST-sorted order
__device__ int g_src[NE];                        // src per dst-sorted edge
__device__ int g_dcnt[NN];                       // in-degree (reset by last round; zero-init at load)
__device__ int g_rowp[NN];                       // dst-CSR row start
__device__ int g_cur[NN];                        // dst scatter cursor

// ---- S0: count dst (edge-parallel) + lin0 init (node range) ----
__global__ __launch_bounds__(256) void k_pre(const int* __restrict__ ei,
                                             const float* __restrict__ x,
                                             const float* __restrict__ lw,
                                             const float* __restrict__ lb) {
    int gid = blockIdx.x * 256 + threadIdx.x;
    atomicAdd(&g_dcnt[ei[NE + gid]], 1);
    if (gid < NN) {
        int n = gid;
        float x0 = x[n * 3 + 0], x1 = x[n * 3 + 1], x2 = x[n * 3 + 2];
        float v[16];
#pragma unroll
        for (int j = 0; j < 16; ++j) {
            float t = lb[j] + x0 * lw[j * 3 + 0] + x1 * lw[j * 3 + 1] + x2 * lw[j * 3 + 2];
            v[j] = fmaxf(t, 0.0f);
        }
#pragma unroll
        for (int j = 0; j < 16; j += 4)
            *(float4*)(g_outA + n * 16 + j) = make_float4(v[j], v[j + 1], v[j + 2], v[j + 3]);
    }
}

// ---- S1: exclusive scan dcnt -> rowp, cur ----
__global__ __launch_bounds__(256) void k_scan() {
    __shared__ int part[256];
    const int C = NN / 256;  // 50
    int t = threadIdx.x;
    int sum = 0;
    for (int i = 0; i < C; ++i) sum += g_dcnt[t * C + i];
    part[t] = sum;
    __syncthreads();
    for (int off = 1; off < 256; off <<= 1) {
        int v = (t >= off) ? part[t - off] : 0;
        __syncthreads();
        part[t] += v;
        __syncthreads();
    }
    int run = (t > 0) ? part[t - 1] : 0;
    for (int i = 0; i < C; ++i) {
        int idx = t * C + i;
        g_rowp[idx] = run;
        g_cur[idx] = run;
        run += g_dcnt[idx];
    }
}

// ---- S2: eh = relu(attr @ nn1_w.T + b1); scatter into dst-sorted slot ----
__global__ __launch_bounds__(256) void k_scatter(const int* __restrict__ ei,
                                                 const float* __restrict__ attr,
                                                 const float* __restrict__ w1,
                                                 const float* __restrict__ b1) {
    int e = blockIdx.x * 256 + threadIdx.x;
    int s = ei[e], d = ei[NE + e];
    float4 a = *(const float4*)(attr + e * 4);
    float v[16];
#pragma unroll
    for (int j = 0; j < 16; ++j) {
        float t = b1[j] + a.x * w1[j * 4 + 0] + a.y * w1[j * 4 + 1] +
                  a.z * w1[j * 4 + 2] + a.w * w1[j * 4 + 3];
        v[j] = fmaxf(t, 0.0f);
    }
    int pos = atomicAdd(&g_cur[d], 1);
    g_src[pos] = s;
#pragma unroll
    for (int j = 0; j < 16; j += 4)
        *(float4*)(g_ehs + pos * 16 + j) = make_float4(v[j], v[j + 1], v[j + 2], v[j + 3]);
}

// ---- one round. 256 thr = 4 waves; 2 nodes/wave (32 lanes/node). ----
// Within a half (one node): sub = edge-subgroup (0/1), j = lane&15.
// Edge loop: sub takes q = sub, sub+2, ... -> serial depth ~deg/2.
// Lane j owns G ROW j: Gd[d] += eh[e,j]*out[src,d]; r16 += out[src,j].
// Combine subs via shfl_xor(16). Contraction split: sub computes k'=8*sub..+8
// (b128 LDS weights), complementary halves meet in 17-stride transpose.
// Node phase (conv+GRU+store) on sub 0 only. No barriers after staging.
__global__ __launch_bounds__(256) void k_round(const float* __restrict__ nn2_w,
                                               const float* __restrict__ nn2_b,
                                               const float* __restrict__ cr,
                                               const float* __restrict__ cb,
                                               const float* __restrict__ wi,
                                               const float* __restrict__ wh,
                                               const float* __restrict__ bi,
                                               const float* __restrict__ bh,
                                               float* __restrict__ out_final,
                                               int flip, int last) {
    // s_W2[j*276 + k'*16 + d] = nn2_w[(d*16+k')*16+j]; bias at [j*276+256+k']
    __shared__ float s_W2[16 * 276];
    __shared__ float s_T[8 * 292];               // per-node transpose + m slot
    __shared__ float s_crT[16 * 20];             // [k*20+d] = cr[d*16+k]
    __shared__ float s_wi[48 * 20], s_wh[48 * 20];  // [row*20+d]
    __shared__ float s_cb[16], s_bi[48], s_bh[48];

    int t = threadIdx.x;
    for (int i = t; i < 4096; i += 256) {
        float v = nn2_w[i];
        int jj = i & 15, mm = i >> 4, kp = mm & 15, d = mm >> 4;
        s_W2[jj * 276 + kp * 16 + d] = v;
    }
    s_W2[(t >> 4) * 276 + 256 + (t & 15)] = nn2_b[t];
    if (t < 256) s_crT[(t & 15) * 20 + (t >> 4)] = cr[t];
    for (int i = t; i < 768; i += 256) {
        s_wi[(i >> 4) * 20 + (i & 15)] = wi[i];
        s_wh[(i >> 4) * 20 + (i & 15)] = wh[i];
    }
    if (t < 16) s_cb[t] = cb[t];
    if (t < 48) { s_bi[t] = bi[t]; s_bh[t] = bh[t]; }
    __syncthreads();

    const float* cur = flip ? g_outB : g_outA;
    float*       nxt = flip ? g_outA : g_outB;

    const int wave = t >> 6, lane = t & 63;
    const int half = lane >> 5;                  // node select within wave
    const int sub  = (lane >> 4) & 1;            // edge subgroup within node
    const int j    = lane & 15;
    const int nidx = wave * 2 + half;            // node slot within block (0..7)
    const int n = blockIdx.x * 8 + nidx;

    int start = g_rowp[n];
    int deg   = g_dcnt[n];
    if (last && (lane & 31) == 0) g_dcnt[n] = 0; // reset for next call's k_pre
    // clamps: no-ops in real runs; guard rocprof-replay state corruption
    start = min(start, NE);
    deg   = min(deg, 128);
    int e_end = min(start + deg, NE);

    // ---- G-row accumulation (registers, zero LDS) ----
    float Gd[16];
#pragma unroll
    for (int d = 0; d < 16; ++d) Gd[d] = 0.0f;
    float r16 = 0.0f;
#pragma unroll 2
    for (int p = start + sub; p < e_end; p += 2) {
        int s = min(g_src[p], NN - 1);           // subgroup-uniform
        const float* orow = cur + s * 16;
        float ej = g_ehs[p * 16 + j];            // 64B coalesced per subgroup
        float4 o0 = *(const float4*)(orow + 0);  // broadcast
        float4 o1 = *(const float4*)(orow + 4);
        float4 o2 = *(const float4*)(orow + 8);
        float4 o3 = *(const float4*)(orow + 12);
        Gd[0]  += ej * o0.x; Gd[1]  += ej * o0.y; Gd[2]  += ej * o0.z; Gd[3]  += ej * o0.w;
        Gd[4]  += ej * o1.x; Gd[5]  += ej * o1.y; Gd[6]  += ej * o1.z; Gd[7]  += ej * o1.w;
        Gd[8]  += ej * o2.x; Gd[9]  += ej * o2.y; Gd[10] += ej * o2.z; Gd[11] += ej * o2.w;
        Gd[12] += ej * o3.x; Gd[13] += ej * o3.y; Gd[14] += ej * o3.z; Gd[15] += ej * o3.w;
        r16 += orow[j];
    }
    // combine edge subgroups (xor 16 stays within the 32-lane half)
#pragma unroll
    for (int d = 0; d < 16; ++d) Gd[d] += __shfl_xor(Gd[d], 16);
    r16 += __shfl_xor(r16, 16);

    // ---- contraction: sub computes k' = 8*sub .. 8*sub+7 (b128 LDS) ----
    const float* wj = s_W2 + j * 276;
    float* Ts = s_T + nidx * 292;
    {
        float part[8];
#pragma unroll
        for (int i = 0; i < 8; ++i) {
            const float* w = wj + (sub * 8 + i) * 16;
            float4 w0 = *(const float4*)(w + 0);
            float4 w1 = *(const float4*)(w + 4);
            float4 w2 = *(const float4*)(w + 8);
            float4 w3 = *(const float4*)(w + 12);
            part[i] = Gd[0] * w0.x + Gd[1] * w0.y + Gd[2] * w0.z + Gd[3] * w0.w
                    + Gd[4] * w1.x + Gd[5] * w1.y + Gd[6] * w1.z + Gd[7] * w1.w
                    + Gd[8] * w2.x + Gd[9] * w2.y + Gd[10] * w2.z + Gd[11] * w2.w
                    + Gd[12] * w3.x + Gd[13] * w3.y + Gd[14] * w3.z + Gd[15] * w3.w;
        }
        // fold bias row: part[i] += r16 * b2[j*16 + 8*sub + i]
        float4 b0 = *(const float4*)(wj + 256 + sub * 8);
        float4 b1 = *(const float4*)(wj + 260 + sub * 8);
        part[0] += r16 * b0.x; part[1] += r16 * b0.y; part[2] += r16 * b0.z; part[3] += r16 * b0.w;
        part[4] += r16 * b1.x; part[5] += r16 * b1.y; part[6] += r16 * b1.z; part[7] += r16 * b1.w;
        // transpose write (17-stride: conflict-free across j)
#pragma unroll
        for (int i = 0; i < 8; ++i) Ts[j * 17 + sub * 8 + i] = part[i];
    }

    // ---- node phase: subgroup 0 only (same wave wrote Ts -> ordered) ----
    if (sub == 0) {
        float aggr = 0.0f;
#pragma unroll
        for (int j2 = 0; j2 < 16; ++j2) aggr += Ts[j2 * 17 + j];
        float invd = 1.0f / (float)(deg > 0 ? deg : 1);
        float a_k = aggr * invd;
        const int k = j;

        const float* nrow = cur + n * 16;
        float4 q0 = *(const float4*)(nrow + 0);
        float4 q1 = *(const float4*)(nrow + 4);
        float4 q2 = *(const float4*)(nrow + 8);
        float4 q3 = *(const float4*)(nrow + 12);
        float o[16] = {q0.x, q0.y, q0.z, q0.w, q1.x, q1.y, q1.z, q1.w,
                       q2.x, q2.y, q2.z, q2.w, q3.x, q3.y, q3.z, q3.w};
        float ok = o[k];

        float mcc = s_cb[k] + a_k;
        {
            const float* c = s_crT + k * 20;
            float4 c0 = *(const float4*)(c + 0);
            float4 c1 = *(const float4*)(c + 4);
            float4 c2 = *(const float4*)(c + 8);
            float4 c3 = *(const float4*)(c + 12);
            mcc += o[0] * c0.x + o[1] * c0.y + o[2] * c0.z + o[3] * c0.w
                 + o[4] * c1.x + o[5] * c1.y + o[6] * c1.z + o[7] * c1.w
                 + o[8] * c2.x + o[9] * c2.y + o[10] * c2.z + o[11] * c2.w
                 + o[12] * c3.x + o[13] * c3.y + o[14] * c3.z + o[15] * c3.w;
        }
        float m = fmaxf(mcc, 0.0f);

        Ts[272 + k] = m;                         // same-wave broadcast slot
        float4 m0 = *(const float4*)(Ts + 272);
        float4 m1 = *(const float4*)(Ts + 276);
        float4 m2 = *(const float4*)(Ts + 280);
        float4 m3 = *(const float4*)(Ts + 284);
        float md[16] = {m0.x, m0.y, m0.z, m0.w, m1.x, m1.y, m1.z, m1.w,
                        m2.x, m2.y, m2.z, m2.w, m3.x, m3.y, m3.z, m3.w};

        float ir = s_bi[k], iz = s_bi[16 + k], in_ = s_bi[32 + k];
        float hr = s_bh[k], hz = s_bh[16 + k], hh = s_bh[32 + k];
#pragma unroll
        for (int g = 0; g < 3; ++g) {
            const float* wrow_i = s_wi + (g * 16 + k) * 20;
            const float* wrow_h = s_wh + (g * 16 + k) * 20;
            float acc_i = 0.0f, acc_h = 0.0f;
#pragma unroll
            for (int d4 = 0; d4 < 4; ++d4) {
                float4 wiv = *(const float4*)(wrow_i + d4 * 4);
                float4 whv = *(const float4*)(wrow_h + d4 * 4);
                acc_i += md[d4 * 4] * wiv.x + md[d4 * 4 + 1] * wiv.y
                       + md[d4 * 4 + 2] * wiv.z + md[d4 * 4 + 3] * wiv.w;
                acc_h += o[d4 * 4] * whv.x + o[d4 * 4 + 1] * whv.y
                       + o[d4 * 4 + 2] * whv.z + o[d4 * 4 + 3] * whv.w;
            }
            if (g == 0) { ir += acc_i; hr += acc_h; }
            else if (g == 1) { iz += acc_i; hz += acc_h; }
            else { in_ += acc_i; hh += acc_h; }
        }
        float rg = 1.0f / (1.0f + __expf(-(ir + hr)));
        float z  = 1.0f / (1.0f + __expf(-(iz + hz)));
        float nh = tanhf(in_ + rg * hh);
        float hnew = (1.0f - z) * nh + z * ok;

        if (last) out_final[n * 16 + k] = hnew;
        else      nxt[n * 16 + k] = hnew;
    }
}

extern "C" void kernel_launch(void* const* d_in, const int* in_sizes, int n_in,
                              void* d_out, int out_size, void* d_ws, size_t ws_size,
                              hipStream_t stream) {
    const float* x         = (const float*)d_in[0];
    const int*   ei        = (const int*)d_in[1];
    const float* edge_attr = (const float*)d_in[2];
    const float* lin0_w    = (const float*)d_in[3];
    const float* lin0_b    = (const float*)d_in[4];
    const float* nn1_w     = (const float*)d_in[5];
    const float* nn1_b     = (const float*)d_in[6];
    const float* nn2_w     = (const float*)d_in[7];
    const float* nn2_b     = (const float*)d_in[8];
    const float* conv_root = (const float*)d_in[9];
    const float* conv_bias = (const float*)d_in[10];
    const float* gru_w_ih  = (const float*)d_in[11];
    const float* gru_w_hh  = (const float*)d_in[12];
    const float* gru_b_ih  = (const float*)d_in[13];
    const float* gru_b_hh  = (const float*)d_in[14];
    float* out = (float*)d_out;

    k_pre<<<NE / 256, 256, 0, stream>>>(ei, x, lin0_w, lin0_b);
    k_scan<<<1, 256, 0, stream>>>();
    k_scatter<<<NE / 256, 256, 0, stream>>>(ei, edge_attr, nn1_w, nn1_b);

    for (int r = 0; r < 6; ++r) {
        k_round<<<NN / 8, 256, 0, stream>>>(nn2_w, nn2_b, conv_root, conv_bias,
                                            gru_w_ih, gru_w_hh, gru_b_ih, gru_b_hh,
                                            out, r & 1, r == 5 ? 1 : 0);
    }
}

// Round 12
// 274.676 us; speedup vs baseline: 1.0282x; 1.0282x over previous
//
#include <hip/hip_runtime.h>

#define NN 12800
#define NE 204800
#define CAP 320   // slab capacity (edges) per block; mean 256, +4 sigma

// ---------------- static device scratch (~14.5 MB) ----------------
__device__ __align__(16) float g_outA[NN * 16];  // node features ping
__device__ __align__(16) float g_outB[NN * 16];  // node features pong
__device__ __align__(16) float g_ehs[NE * 16];   // edge hidden, DST-sorted order
__device__ int g_src[NE];                        // src per dst-sorted edge
__device__ int g_dcnt[NN];                       // in-degree (reset by last round; zero-init at load)
__device__ int g_rowp[NN];                       // dst-CSR row start
__device__ int g_cur[NN];                        // dst scatter cursor

// ---- S0: count dst (edge-parallel) + lin0 init (node range) ----
__global__ __launch_bounds__(256) void k_pre(const int* __restrict__ ei,
                                             const float* __restrict__ x,
                                             const float* __restrict__ lw,
                                             const float* __restrict__ lb) {
    int gid = blockIdx.x * 256 + threadIdx.x;
    atomicAdd(&g_dcnt[ei[NE + gid]], 1);
    if (gid < NN) {
        int n = gid;
        float x0 = x[n * 3 + 0], x1 = x[n * 3 + 1], x2 = x[n * 3 + 2];
        float v[16];
#pragma unroll
        for (int j = 0; j < 16; ++j) {
            float t = lb[j] + x0 * lw[j * 3 + 0] + x1 * lw[j * 3 + 1] + x2 * lw[j * 3 + 2];
            v[j] = fmaxf(t, 0.0f);
        }
#pragma unroll
        for (int j = 0; j < 16; j += 4)
            *(float4*)(g_outA + n * 16 + j) = make_float4(v[j], v[j + 1], v[j + 2], v[j + 3]);
    }
}

// ---- S1: exclusive scan dcnt -> rowp, cur ----
__global__ __launch_bounds__(256) void k_scan() {
    __shared__ int part[256];
    const int C = NN / 256;  // 50
    int t = threadIdx.x;
    int sum = 0;
    for (int i = 0; i < C; ++i) sum += g_dcnt[t * C + i];
    part[t] = sum;
    __syncthreads();
    for (int off = 1; off < 256; off <<= 1) {
        int v = (t >= off) ? part[t - off] : 0;
        __syncthreads();
        part[t] += v;
        __syncthreads();
    }
    int run = (t > 0) ? part[t - 1] : 0;
    for (int i = 0; i < C; ++i) {
        int idx = t * C + i;
        g_rowp[idx] = run;
        g_cur[idx] = run;
        run += g_dcnt[idx];
    }
}

// ---- S2: eh = relu(attr @ nn1_w.T + b1); scatter into dst-sorted slot ----
__global__ __launch_bounds__(256) void k_scatter(const int* __restrict__ ei,
                                                 const float* __restrict__ attr,
                                                 const float* __restrict__ w1,
                                                 const float* __restrict__ b1) {
    int e = blockIdx.x * 256 + threadIdx.x;
    int s = ei[e], d = ei[NE + e];
    float4 a = *(const float4*)(attr + e * 4);
    float v[16];
#pragma unroll
    for (int j = 0; j < 16; ++j) {
        float t = b1[j] + a.x * w1[j * 4 + 0] + a.y * w1[j * 4 + 1] +
                  a.z * w1[j * 4 + 2] + a.w * w1[j * 4 + 3];
        v[j] = fmaxf(t, 0.0f);
    }
    int pos = atomicAdd(&g_cur[d], 1);
    g_src[pos] = s;
#pragma unroll
    for (int j = 0; j < 16; j += 4)
        *(float4*)(g_ehs + pos * 16 + j) = make_float4(v[j], v[j + 1], v[j + 2], v[j + 3]);
}

// ---- one round. 256 thr = 16 nodes x 16 lanes; block owns contiguous edges.
// Phase 1: cooperative slab gather of out[src] into LDS (parallel, no chains).
// Phase 2: per-node edge loop reads slab (b128 broadcast) + eh (global stream);
// lane j owns G row j in registers; contraction via b128 s_W2; s_T overlays
// the slab (after barrier) for the j-transpose reduce; conv+GRU as R10.
__global__ __launch_bounds__(256) void k_round(const float* __restrict__ nn2_w,
                                               const float* __restrict__ nn2_b,
                                               const float* __restrict__ cr,
                                               const float* __restrict__ cb,
                                               const float* __restrict__ wi,
                                               const float* __restrict__ wh,
                                               const float* __restrict__ bi,
                                               const float* __restrict__ bh,
                                               float* __restrict__ out_final,
                                               int flip, int last) {
    __shared__ float s_W2[16 * 276];             // [j*276 + k'*16 + d]; bias at +256
    __shared__ float s_dyn[CAP * 20];            // slab [e*20+d]; later s_T overlay
    __shared__ float s_crT[16 * 20];             // [k*20+d] = cr[d*16+k]
    __shared__ float s_wi[48 * 20], s_wh[48 * 20];  // [row*20+d]
    __shared__ float s_cb[16], s_bi[48], s_bh[48];

    int t = threadIdx.x;
    for (int i = t; i < 4096; i += 256) {
        float v = nn2_w[i];
        int jj = i & 15, mm = i >> 4, kp = mm & 15, d = mm >> 4;
        s_W2[jj * 276 + kp * 16 + d] = v;
    }
    s_W2[(t >> 4) * 276 + 256 + (t & 15)] = nn2_b[t];
    if (t < 256) s_crT[(t & 15) * 20 + (t >> 4)] = cr[t];
    for (int i = t; i < 768; i += 256) {
        s_wi[(i >> 4) * 20 + (i & 15)] = wi[i];
        s_wh[(i >> 4) * 20 + (i & 15)] = wh[i];
    }
    if (t < 16) s_cb[t] = cb[t];
    if (t < 48) { s_bi[t] = bi[t]; s_bh[t] = bh[t]; }

    const float* cur = flip ? g_outB : g_outA;
    float*       nxt = flip ? g_outA : g_outB;

    // ---- phase 1: slab gather (independent loads, thread per edge) ----
    const int n0 = blockIdx.x * 16;
    int base = min(g_rowp[n0], NE);
    int cend = (n0 + 16 < NN) ? min(g_rowp[n0 + 16], NE) : NE;
    int count = max(cend - base, 0);
    int gcount = min(count, CAP);
    for (int i = t; i < gcount; i += 256) {
        int s = min(g_src[base + i], NN - 1);
        const float* orow = cur + s * 16;
        float4 o0 = *(const float4*)(orow + 0);
        float4 o1 = *(const float4*)(orow + 4);
        float4 o2 = *(const float4*)(orow + 8);
        float4 o3 = *(const float4*)(orow + 12);
        float* dst = s_dyn + i * 20;
        *(float4*)(dst + 0)  = o0;
        *(float4*)(dst + 4)  = o1;
        *(float4*)(dst + 8)  = o2;
        *(float4*)(dst + 12) = o3;
    }
    __syncthreads();

    // ---- phase 2: per-node G accumulation from slab ----
    const int grp = t >> 4, j = t & 15;
    const int n = n0 + grp;
    int start = min(g_rowp[n], NE);
    int deg   = min(g_dcnt[n], 128);
    if (last && j == 0) g_dcnt[n] = 0;           // reset for next call's k_pre
    int e_end = min(start + deg, NE);

    float Gd[16];
#pragma unroll
    for (int d = 0; d < 16; ++d) Gd[d] = 0.0f;
    float r16 = 0.0f;
#pragma unroll 2
    for (int p = start; p < e_end; ++p) {
        int el = p - base;
        float ej = g_ehs[p * 16 + j];            // global, sequential, coalesced
        float4 o0, o1, o2, o3; float rj;
        if (el < CAP) {                          // always, in practice
            const float* orow = s_dyn + el * 20; // group-uniform -> LDS broadcast
            o0 = *(const float4*)(orow + 0);
            o1 = *(const float4*)(orow + 4);
            o2 = *(const float4*)(orow + 8);
            o3 = *(const float4*)(orow + 12);
            rj = orow[j];
        } else {                                 // overflow fallback (rare)
            int s = min(g_src[p], NN - 1);
            const float* orow = cur + s * 16;
            o0 = *(const float4*)(orow + 0);
            o1 = *(const float4*)(orow + 4);
            o2 = *(const float4*)(orow + 8);
            o3 = *(const float4*)(orow + 12);
            rj = orow[j];
        }
        Gd[0]  += ej * o0.x; Gd[1]  += ej * o0.y; Gd[2]  += ej * o0.z; Gd[3]  += ej * o0.w;
        Gd[4]  += ej * o1.x; Gd[5]  += ej * o1.y; Gd[6]  += ej * o1.z; Gd[7]  += ej * o1.w;
        Gd[8]  += ej * o2.x; Gd[9]  += ej * o2.y; Gd[10] += ej * o2.z; Gd[11] += ej * o2.w;
        Gd[12] += ej * o3.x; Gd[13] += ej * o3.y; Gd[14] += ej * o3.z; Gd[15] += ej * o3.w;
        r16 += rj;
    }

    // ---- contraction: part[k'] via b128 s_W2 reads (registers only) ----
    const float* wj = s_W2 + j * 276;
    float part[16];
#pragma unroll
    for (int kp = 0; kp < 16; ++kp) {
        const float* w = wj + kp * 16;
        float4 w0 = *(const float4*)(w + 0);
        float4 w1 = *(const float4*)(w + 4);
        float4 w2 = *(const float4*)(w + 8);
        float4 w3 = *(const float4*)(w + 12);
        part[kp] = Gd[0] * w0.x + Gd[1] * w0.y + Gd[2] * w0.z + Gd[3] * w0.w
                 + Gd[4] * w1.x + Gd[5] * w1.y + Gd[6] * w1.z + Gd[7] * w1.w
                 + Gd[8] * w2.x + Gd[9] * w2.y + Gd[10] * w2.z + Gd[11] * w2.w
                 + Gd[12] * w3.x + Gd[13] * w3.y + Gd[14] * w3.z + Gd[15] * w3.w;
    }
    {   // fold bias row: part[k'] += r16 * b2[j*16+k']
        float4 b0 = *(const float4*)(wj + 256);
        float4 b1 = *(const float4*)(wj + 260);
        float4 b2v = *(const float4*)(wj + 264);
        float4 b3 = *(const float4*)(wj + 268);
        part[0] += r16 * b0.x;  part[1] += r16 * b0.y;  part[2] += r16 * b0.z;  part[3] += r16 * b0.w;
        part[4] += r16 * b1.x;  part[5] += r16 * b1.y;  part[6] += r16 * b1.z;  part[7] += r16 * b1.w;
        part[8] += r16 * b2v.x; part[9] += r16 * b2v.y; part[10] += r16 * b2v.z; part[11] += r16 * b2v.w;
        part[12] += r16 * b3.x; part[13] += r16 * b3.y; part[14] += r16 * b3.z; part[15] += r16 * b3.w;
    }
    __syncthreads();                             // slab dead -> s_T overlay

    // ---- transpose-reduce over j (same-wave, no barrier) ----
    float* Ts = s_dyn + grp * 292;
#pragma unroll
    for (int k2 = 0; k2 < 16; ++k2) Ts[j * 17 + k2] = part[k2];
    float aggr = 0.0f;
#pragma unroll
    for (int j2 = 0; j2 < 16; ++j2) aggr += Ts[j2 * 17 + j];
    float invd = 1.0f / (float)(deg > 0 ? deg : 1);
    float a_k = aggr * invd;
    const int k = j;

    // ---- node update: conv + GRU (b128 LDS weights) ----
    const float* nrow = cur + n * 16;
    float4 q0 = *(const float4*)(nrow + 0);
    float4 q1 = *(const float4*)(nrow + 4);
    float4 q2 = *(const float4*)(nrow + 8);
    float4 q3 = *(const float4*)(nrow + 12);
    float o[16] = {q0.x, q0.y, q0.z, q0.w, q1.x, q1.y, q1.z, q1.w,
                   q2.x, q2.y, q2.z, q2.w, q3.x, q3.y, q3.z, q3.w};
    float ok = o[k];

    float mcc = s_cb[k] + a_k;
    {
        const float* c = s_crT + k * 20;
        float4 c0 = *(const float4*)(c + 0);
        float4 c1 = *(const float4*)(c + 4);
        float4 c2 = *(const float4*)(c + 8);
        float4 c3 = *(const float4*)(c + 12);
        mcc += o[0] * c0.x + o[1] * c0.y + o[2] * c0.z + o[3] * c0.w
             + o[4] * c1.x + o[5] * c1.y + o[6] * c1.z + o[7] * c1.w
             + o[8] * c2.x + o[9] * c2.y + o[10] * c2.z + o[11] * c2.w
             + o[12] * c3.x + o[13] * c3.y + o[14] * c3.z + o[15] * c3.w;
    }
    float m = fmaxf(mcc, 0.0f);

    Ts[272 + k] = m;                             // same-wave broadcast slot
    float4 m0 = *(const float4*)(Ts + 272);
    float4 m1 = *(const float4*)(Ts + 276);
    float4 m2 = *(const float4*)(Ts + 280);
    float4 m3 = *(const float4*)(Ts + 284);
    float md[16] = {m0.x, m0.y, m0.z, m0.w, m1.x, m1.y, m1.z, m1.w,
                    m2.x, m2.y, m2.z, m2.w, m3.x, m3.y, m3.z, m3.w};

    float ir = s_bi[k], iz = s_bi[16 + k], in_ = s_bi[32 + k];
    float hr = s_bh[k], hz = s_bh[16 + k], hh = s_bh[32 + k];
#pragma unroll
    for (int g = 0; g < 3; ++g) {
        const float* wrow_i = s_wi + (g * 16 + k) * 20;
        const float* wrow_h = s_wh + (g * 16 + k) * 20;
        float acc_i = 0.0f, acc_h = 0.0f;
#pragma unroll
        for (int d4 = 0; d4 < 4; ++d4) {
            float4 wiv = *(const float4*)(wrow_i + d4 * 4);
            float4 whv = *(const float4*)(wrow_h + d4 * 4);
            acc_i += md[d4 * 4] * wiv.x + md[d4 * 4 + 1] * wiv.y
                   + md[d4 * 4 + 2] * wiv.z + md[d4 * 4 + 3] * wiv.w;
            acc_h += o[d4 * 4] * whv.x + o[d4 * 4 + 1] * whv.y
                   + o[d4 * 4 + 2] * whv.z + o[d4 * 4 + 3] * whv.w;
        }
        if (g == 0) { ir += acc_i; hr += acc_h; }
        else if (g == 1) { iz += acc_i; hz += acc_h; }
        else { in_ += acc_i; hh += acc_h; }
    }
    float rg = 1.0f / (1.0f + __expf(-(ir + hr)));
    float z  = 1.0f / (1.0f + __expf(-(iz + hz)));
    float nh = tanhf(in_ + rg * hh);
    float hnew = (1.0f - z) * nh + z * ok;

    if (last) out_final[n * 16 + k] = hnew;
    else      nxt[n * 16 + k] = hnew;
}

extern "C" void kernel_launch(void* const* d_in, const int* in_sizes, int n_in,
                              void* d_out, int out_size, void* d_ws, size_t ws_size,
                              hipStream_t stream) {
    const float* x         = (const float*)d_in[0];
    const int*   ei        = (const int*)d_in[1];
    const float* edge_attr = (const float*)d_in[2];
    const float* lin0_w    = (const float*)d_in[3];
    const float* lin0_b    = (const float*)d_in[4];
    const float* nn1_w     = (const float*)d_in[5];
    const float* nn1_b     = (const float*)d_in[6];
    const float* nn2_w     = (const float*)d_in[7];
    const float* nn2_b     = (const float*)d_in[8];
    const float* conv_root = (const float*)d_in[9];
    const float* conv_bias = (const float*)d_in[10];
    const float* gru_w_ih  = (const float*)d_in[11];
    const float* gru_w_hh  = (const float*)d_in[12];
    const float* gru_b_ih  = (const float*)d_in[13];
    const float* gru_b_hh  = (const float*)d_in[14];
    float* out = (float*)d_out;

    k_pre<<<NE / 256, 256, 0, stream>>>(ei, x, lin0_w, lin0_b);
    k_scan<<<1, 256, 0, stream>>>();
    k_scatter<<<NE / 256, 256, 0, stream>>>(ei, edge_attr, nn1_w, nn1_b);

    for (int r = 0; r < 6; ++r) {
        k_round<<<NN / 16, 256, 0, stream>>>(nn2_w, nn2_b, conv_root, conv_bias,
                                             gru_w_ih, gru_w_hh, gru_b_ih, gru_b_hh,
                                             out, r & 1, r == 5 ? 1 : 0);
    }
}

// Round 13
// 266.175 us; speedup vs baseline: 1.0610x; 1.0319x over previous
//
#include <hip/hip_runtime.h>

#define NN 12800
#define NE 204800

// ---------------- static device scratch (~14.5 MB) ----------------
__device__ __align__(16) float g_outA[NN * 16];  // node features ping
__device__ __align__(16) float g_outB[NN * 16];  // node features pong
__device__ __align__(16) float g_ehs[NE * 16];   // edge hidden, DST-sorted order
__device__ int g_src[NE];                        // src per dst-sorted edge
__device__ int g_dcnt[NN];                       // in-degree (reset by last round; zero-init at load)
__device__ int g_rowp[NN];                       // dst-CSR row start
__device__ int g_cur[NN];                        // dst scatter cursor

// ---- S0: count dst (edge-parallel) + lin0 init (node range) ----
__global__ __launch_bounds__(256) void k_pre(const int* __restrict__ ei,
                                             const float* __restrict__ x,
                                             const float* __restrict__ lw,
                                             const float* __restrict__ lb) {
    int gid = blockIdx.x * 256 + threadIdx.x;
    atomicAdd(&g_dcnt[ei[NE + gid]], 1);
    if (gid < NN) {
        int n = gid;
        float x0 = x[n * 3 + 0], x1 = x[n * 3 + 1], x2 = x[n * 3 + 2];
        float v[16];
#pragma unroll
        for (int j = 0; j < 16; ++j) {
            float t = lb[j] + x0 * lw[j * 3 + 0] + x1 * lw[j * 3 + 1] + x2 * lw[j * 3 + 2];
            v[j] = fmaxf(t, 0.0f);
        }
#pragma unroll
        for (int j = 0; j < 16; j += 4)
            *(float4*)(g_outA + n * 16 + j) = make_float4(v[j], v[j + 1], v[j + 2], v[j + 3]);
    }
}

// ---- S1: exclusive scan dcnt -> rowp, cur ----
__global__ __launch_bounds__(256) void k_scan() {
    __shared__ int part[256];
    const int C = NN / 256;  // 50
    int t = threadIdx.x;
    int sum = 0;
    for (int i = 0; i < C; ++i) sum += g_dcnt[t * C + i];
    part[t] = sum;
    __syncthreads();
    for (int off = 1; off < 256; off <<= 1) {
        int v = (t >= off) ? part[t - off] : 0;
        __syncthreads();
        part[t] += v;
        __syncthreads();
    }
    int run = (t > 0) ? part[t - 1] : 0;
    for (int i = 0; i < C; ++i) {
        int idx = t * C + i;
        g_rowp[idx] = run;
        g_cur[idx] = run;
        run += g_dcnt[idx];
    }
}

// ---- S2: eh = relu(attr @ nn1_w.T + b1); scatter into dst-sorted slot ----
__global__ __launch_bounds__(256) void k_scatter(const int* __restrict__ ei,
                                                 const float* __restrict__ attr,
                                                 const float* __restrict__ w1,
                                                 const float* __restrict__ b1) {
    int e = blockIdx.x * 256 + threadIdx.x;
    int s = ei[e], d = ei[NE + e];
    float4 a = *(const float4*)(attr + e * 4);
    float v[16];
#pragma unroll
    for (int j = 0; j < 16; ++j) {
        float t = b1[j] + a.x * w1[j * 4 + 0] + a.y * w1[j * 4 + 1] +
                  a.z * w1[j * 4 + 2] + a.w * w1[j * 4 + 3];
        v[j] = fmaxf(t, 0.0f);
    }
    int pos = atomicAdd(&g_cur[d], 1);
    g_src[pos] = s;
#pragma unroll
    for (int j = 0; j < 16; j += 4)
        *(float4*)(g_ehs + pos * 16 + j) = make_float4(v[j], v[j + 1], v[j + 2], v[j + 3]);
}

// ---- one round. 256 thr = 16 nodes x 16 lanes. NO s_T: shuffle reduce. ----
// Lane j owns G ROW j in registers. Contraction -> part[k'] (b128 s_W2).
// j-reduction: 4-stage halving butterfly (15 shfl_xor), lands a[k] at lane k.
// m-broadcast via __shfl(m, d, 16). LDS ~27.5 KB -> 5 blocks/CU capacity.
__global__ __launch_bounds__(256) void k_round(const float* __restrict__ nn2_w,
                                               const float* __restrict__ nn2_b,
                                               const float* __restrict__ cr,
                                               const float* __restrict__ cb,
                                               const float* __restrict__ wi,
                                               const float* __restrict__ wh,
                                               const float* __restrict__ bi,
                                               const float* __restrict__ bh,
                                               float* __restrict__ out_final,
                                               int flip, int last) {
    // s_W2[j*276 + k'*16 + d] = nn2_w[(d*16+k')*16+j]; bias at [j*276+256+k']
    __shared__ float s_W2[16 * 276];
    __shared__ float s_crT[16 * 20];             // [k*20+d] = cr[d*16+k]
    __shared__ float s_wi[48 * 20], s_wh[48 * 20];  // [row*20+d]
    __shared__ float s_cb[16], s_bi[48], s_bh[48];

    int t = threadIdx.x;
    for (int i = t; i < 4096; i += 256) {
        float v = nn2_w[i];
        int jj = i & 15, mm = i >> 4, kp = mm & 15, d = mm >> 4;
        s_W2[jj * 276 + kp * 16 + d] = v;
    }
    s_W2[(t >> 4) * 276 + 256 + (t & 15)] = nn2_b[t];
    if (t < 256) s_crT[(t & 15) * 20 + (t >> 4)] = cr[t];
    for (int i = t; i < 768; i += 256) {
        s_wi[(i >> 4) * 20 + (i & 15)] = wi[i];
        s_wh[(i >> 4) * 20 + (i & 15)] = wh[i];
    }
    if (t < 16) s_cb[t] = cb[t];
    if (t < 48) { s_bi[t] = bi[t]; s_bh[t] = bh[t]; }
    __syncthreads();

    const float* cur = flip ? g_outB : g_outA;
    float*       nxt = flip ? g_outA : g_outB;

    const int grp = t >> 4, j = t & 15;          // lane j inside group
    const int n = blockIdx.x * 16 + grp;
    int start = min(g_rowp[n], NE);
    int deg   = min(g_dcnt[n], 128);
    if (last && j == 0) g_dcnt[n] = 0;           // reset for next call's k_pre
    int e_end = min(start + deg, NE);

    // ---- G-row accumulation (registers, zero LDS) ----
    float Gd[16];
#pragma unroll
    for (int d = 0; d < 16; ++d) Gd[d] = 0.0f;
    float r16 = 0.0f;
#pragma unroll 4
    for (int p = start; p < e_end; ++p) {
        int s = min(g_src[p], NN - 1);           // group-uniform
        const float* orow = cur + s * 16;
        float ej = g_ehs[p * 16 + j];            // coalesced 64B per group
        float4 o0 = *(const float4*)(orow + 0);  // broadcast
        float4 o1 = *(const float4*)(orow + 4);
        float4 o2 = *(const float4*)(orow + 8);
        float4 o3 = *(const float4*)(orow + 12);
        Gd[0]  += ej * o0.x; Gd[1]  += ej * o0.y; Gd[2]  += ej * o0.z; Gd[3]  += ej * o0.w;
        Gd[4]  += ej * o1.x; Gd[5]  += ej * o1.y; Gd[6]  += ej * o1.z; Gd[7]  += ej * o1.w;
        Gd[8]  += ej * o2.x; Gd[9]  += ej * o2.y; Gd[10] += ej * o2.z; Gd[11] += ej * o2.w;
        Gd[12] += ej * o3.x; Gd[13] += ej * o3.y; Gd[14] += ej * o3.z; Gd[15] += ej * o3.w;
        r16 += orow[j];
    }

    // ---- contraction: part[k'] via b128 s_W2 reads ----
    const float* wj = s_W2 + j * 276;
    float part[16];
#pragma unroll
    for (int kp = 0; kp < 16; ++kp) {
        const float* w = wj + kp * 16;
        float4 w0 = *(const float4*)(w + 0);
        float4 w1 = *(const float4*)(w + 4);
        float4 w2 = *(const float4*)(w + 8);
        float4 w3 = *(const float4*)(w + 12);
        part[kp] = Gd[0] * w0.x + Gd[1] * w0.y + Gd[2] * w0.z + Gd[3] * w0.w
                 + Gd[4] * w1.x + Gd[5] * w1.y + Gd[6] * w1.z + Gd[7] * w1.w
                 + Gd[8] * w2.x + Gd[9] * w2.y + Gd[10] * w2.z + Gd[11] * w2.w
                 + Gd[12] * w3.x + Gd[13] * w3.y + Gd[14] * w3.z + Gd[15] * w3.w;
    }
    {   // fold bias row: part[k'] += r16 * b2[j*16+k']
        float4 b0 = *(const float4*)(wj + 256);
        float4 b1 = *(const float4*)(wj + 260);
        float4 b2v = *(const float4*)(wj + 264);
        float4 b3 = *(const float4*)(wj + 268);
        part[0] += r16 * b0.x;  part[1] += r16 * b0.y;  part[2] += r16 * b0.z;  part[3] += r16 * b0.w;
        part[4] += r16 * b1.x;  part[5] += r16 * b1.y;  part[6] += r16 * b1.z;  part[7] += r16 * b1.w;
        part[8] += r16 * b2v.x; part[9] += r16 * b2v.y; part[10] += r16 * b2v.z; part[11] += r16 * b2v.w;
        part[12] += r16 * b3.x; part[13] += r16 * b3.y; part[14] += r16 * b3.z; part[15] += r16 * b3.w;
    }

    // ---- j-reduction: halving butterfly, 15 shfl_xor; lane j ends with a[j] --
    float w8[8];
#pragma unroll
    for (int i = 0; i < 8; ++i) {
        int keep = 2 * i + (j & 1);
        w8[i] = part[keep] + __shfl_xor(part[keep ^ 1], 1);
    }
    float w4[4];
#pragma unroll
    for (int i = 0; i < 4; ++i) {
        int keep = 2 * i + ((j >> 1) & 1);
        w4[i] = w8[keep] + __shfl_xor(w8[keep ^ 1], 2);
    }
    float w2[2];
#pragma unroll
    for (int i = 0; i < 2; ++i) {
        int keep = 2 * i + ((j >> 2) & 1);
        w2[i] = w4[keep] + __shfl_xor(w4[keep ^ 1], 4);
    }
    float aggr;
    {
        int keep = (j >> 3) & 1;
        aggr = w2[keep] + __shfl_xor(w2[keep ^ 1], 8);
    }
    float invd = 1.0f / (float)(deg > 0 ? deg : 1);
    float a_k = aggr * invd;
    const int k = j;

    // ---- node update: conv + GRU (b128 LDS weights) ----
    const float* nrow = cur + n * 16;
    float4 q0 = *(const float4*)(nrow + 0);
    float4 q1 = *(const float4*)(nrow + 4);
    float4 q2 = *(const float4*)(nrow + 8);
    float4 q3 = *(const float4*)(nrow + 12);
    float o[16] = {q0.x, q0.y, q0.z, q0.w, q1.x, q1.y, q1.z, q1.w,
                   q2.x, q2.y, q2.z, q2.w, q3.x, q3.y, q3.z, q3.w};
    float ok = o[k];

    float mcc = s_cb[k] + a_k;
    {
        const float* c = s_crT + k * 20;
        float4 c0 = *(const float4*)(c + 0);
        float4 c1 = *(const float4*)(c + 4);
        float4 c2 = *(const float4*)(c + 8);
        float4 c3 = *(const float4*)(c + 12);
        mcc += o[0] * c0.x + o[1] * c0.y + o[2] * c0.z + o[3] * c0.w
             + o[4] * c1.x + o[5] * c1.y + o[6] * c1.z + o[7] * c1.w
             + o[8] * c2.x + o[9] * c2.y + o[10] * c2.z + o[11] * c2.w
             + o[12] * c3.x + o[13] * c3.y + o[14] * c3.z + o[15] * c3.w;
    }
    float m = fmaxf(mcc, 0.0f);

    // broadcast m across the 16-lane group (register path, no LDS)
    float md[16];
#pragma unroll
    for (int d = 0; d < 16; ++d) md[d] = __shfl(m, d, 16);

    float ir = s_bi[k], iz = s_bi[16 + k], in_ = s_bi[32 + k];
    float hr = s_bh[k], hz = s_bh[16 + k], hh = s_bh[32 + k];
#pragma unroll
    for (int g = 0; g < 3; ++g) {
        const float* wrow_i = s_wi + (g * 16 + k) * 20;
        const float* wrow_h = s_wh + (g * 16 + k) * 20;
        float acc_i = 0.0f, acc_h = 0.0f;
#pragma unroll
        for (int d4 = 0; d4 < 4; ++d4) {
            float4 wiv = *(const float4*)(wrow_i + d4 * 4);
            float4 whv = *(const float4*)(wrow_h + d4 * 4);
            acc_i += md[d4 * 4] * wiv.x + md[d4 * 4 + 1] * wiv.y
                   + md[d4 * 4 + 2] * wiv.z + md[d4 * 4 + 3] * wiv.w;
            acc_h += o[d4 * 4] * whv.x + o[d4 * 4 + 1] * whv.y
                   + o[d4 * 4 + 2] * whv.z + o[d4 * 4 + 3] * whv.w;
        }
        if (g == 0) { ir += acc_i; hr += acc_h; }
        else if (g == 1) { iz += acc_i; hz += acc_h; }
        else { in_ += acc_i; hh += acc_h; }
    }
    float rg = 1.0f / (1.0f + __expf(-(ir + hr)));
    float z  = 1.0f / (1.0f + __expf(-(iz + hz)));
    float nh = tanhf(in_ + rg * hh);
    float hnew = (1.0f - z) * nh + z * ok;

    if (last) out_final[n * 16 + k] = hnew;
    else      nxt[n * 16 + k] = hnew;
}

extern "C" void kernel_launch(void* const* d_in, const int* in_sizes, int n_in,
                              void* d_out, int out_size, void* d_ws, size_t ws_size,
                              hipStream_t stream) {
    const float* x         = (const float*)d_in[0];
    const int*   ei        = (const int*)d_in[1];
    const float* edge_attr = (const float*)d_in[2];
    const float* lin0_w    = (const float*)d_in[3];
    const float* lin0_b    = (const float*)d_in[4];
    const float* nn1_w     = (const float*)d_in[5];
    const float* nn1_b     = (const float*)d_in[6];
    const float* nn2_w     = (const float*)d_in[7];
    const float* nn2_b     = (const float*)d_in[8];
    const float* conv_root = (const float*)d_in[9];
    const float* conv_bias = (const float*)d_in[10];
    const float* gru_w_ih  = (const float*)d_in[11];
    const float* gru_w_hh  = (const float*)d_in[12];
    const float* gru_b_ih  = (const float*)d_in[13];
    const float* gru_b_hh  = (const float*)d_in[14];
    float* out = (float*)d_out;

    k_pre<<<NE / 256, 256, 0, stream>>>(ei, x, lin0_w, lin0_b);
    k_scan<<<1, 256, 0, stream>>>();
    k_scatter<<<NE / 256, 256, 0, stream>>>(ei, edge_attr, nn1_w, nn1_b);

    for (int r = 0; r < 6; ++r) {
        k_round<<<NN / 16, 256, 0, stream>>>(nn2_w, nn2_b, conv_root, conv_bias,
                                             gru_w_ih, gru_w_hh, gru_b_ih, gru_b_hh,
                                             out, r & 1, r == 5 ? 1 : 0);
    }
}

// Round 14
// 252.163 us; speedup vs baseline: 1.1200x; 1.0556x over previous
//
#include <hip/hip_runtime.h>

#define NN 12800
#define NE 204800
#define BCAP 64   // bucket capacity per node; Poisson(16), P(>64) ~ 1e-18

// ---------------- static device scratch (~57 MB) ----------------
__device__ __align__(16) float g_outA[NN * 16];        // node features ping
__device__ __align__(16) float g_outB[NN * 16];        // node features pong
__device__ __align__(16) float g_ehsB[NN * BCAP * 16]; // eh buckets, dst-grouped
__device__ int g_srcB[NN * BCAP];                      // src per bucket slot
__device__ int g_cnt[NN];                              // in-degree / cursor
                                                       // (reset by last round; zero-init at load)

// ---- S0: lin0 (node range) + eh compute + bucket scatter (edge-parallel) ----
__global__ __launch_bounds__(256) void k_setup(const int* __restrict__ ei,
                                               const float* __restrict__ x,
                                               const float* __restrict__ lw,
                                               const float* __restrict__ lb,
                                               const float* __restrict__ attr,
                                               const float* __restrict__ w1,
                                               const float* __restrict__ b1) {
    int gid = blockIdx.x * 256 + threadIdx.x;

    // lin0 for the node range
    if (gid < NN) {
        int n = gid;
        float x0 = x[n * 3 + 0], x1 = x[n * 3 + 1], x2 = x[n * 3 + 2];
        float v[16];
#pragma unroll
        for (int j = 0; j < 16; ++j) {
            float t = lb[j] + x0 * lw[j * 3 + 0] + x1 * lw[j * 3 + 1] + x2 * lw[j * 3 + 2];
            v[j] = fmaxf(t, 0.0f);
        }
#pragma unroll
        for (int j = 0; j < 16; j += 4)
            *(float4*)(g_outA + n * 16 + j) = make_float4(v[j], v[j + 1], v[j + 2], v[j + 3]);
    }

    // eh + scatter into dst bucket
    int e = gid;
    int s = ei[e], d = ei[NE + e];
    float4 a = *(const float4*)(attr + e * 4);
    float v[16];
#pragma unroll
    for (int j = 0; j < 16; ++j) {
        float t = b1[j] + a.x * w1[j * 4 + 0] + a.y * w1[j * 4 + 1] +
                  a.z * w1[j * 4 + 2] + a.w * w1[j * 4 + 3];
        v[j] = fmaxf(t, 0.0f);
    }
    int pos = atomicAdd(&g_cnt[d], 1);
    if (pos < BCAP) {
        int slot = d * BCAP + pos;
        g_srcB[slot] = s;
#pragma unroll
        for (int j = 0; j < 16; j += 4)
            *(float4*)(g_ehsB + slot * 16 + j) = make_float4(v[j], v[j + 1], v[j + 2], v[j + 3]);
    }
}

// ---- one round. 256 thr = 16 nodes x 16 lanes. R13 internals + buckets. ----
__global__ __launch_bounds__(256) void k_round(const float* __restrict__ nn2_w,
                                               const float* __restrict__ nn2_b,
                                               const float* __restrict__ cr,
                                               const float* __restrict__ cb,
                                               const float* __restrict__ wi,
                                               const float* __restrict__ wh,
                                               const float* __restrict__ bi,
                                               const float* __restrict__ bh,
                                               float* __restrict__ out_final,
                                               int flip, int last) {
    // s_W2[j*276 + k'*16 + d] = nn2_w[(d*16+k')*16+j]; bias at [j*276+256+k']
    __shared__ float s_W2[16 * 276];
    __shared__ float s_crT[16 * 20];             // [k*20+d] = cr[d*16+k]
    __shared__ float s_wi[48 * 20], s_wh[48 * 20];  // [row*20+d]
    __shared__ float s_cb[16], s_bi[48], s_bh[48];

    int t = threadIdx.x;
    for (int i = t; i < 4096; i += 256) {
        float v = nn2_w[i];
        int jj = i & 15, mm = i >> 4, kp = mm & 15, d = mm >> 4;
        s_W2[jj * 276 + kp * 16 + d] = v;
    }
    s_W2[(t >> 4) * 276 + 256 + (t & 15)] = nn2_b[t];
    if (t < 256) s_crT[(t & 15) * 20 + (t >> 4)] = cr[t];
    for (int i = t; i < 768; i += 256) {
        s_wi[(i >> 4) * 20 + (i & 15)] = wi[i];
        s_wh[(i >> 4) * 20 + (i & 15)] = wh[i];
    }
    if (t < 16) s_cb[t] = cb[t];
    if (t < 48) { s_bi[t] = bi[t]; s_bh[t] = bh[t]; }
    __syncthreads();

    const float* cur = flip ? g_outB : g_outA;
    float*       nxt = flip ? g_outA : g_outB;

    const int grp = t >> 4, j = t & 15;          // lane j inside group
    const int n = blockIdx.x * 16 + grp;
    int deg = min(g_cnt[n], BCAP);               // clamp guards replay corruption
    if (last && j == 0) g_cnt[n] = 0;            // reset for next call's k_setup
    const int base = n * BCAP;

    // ---- G-row accumulation (registers, zero LDS) ----
    float Gd[16];
#pragma unroll
    for (int d = 0; d < 16; ++d) Gd[d] = 0.0f;
    float r16 = 0.0f;
#pragma unroll 4
    for (int q = 0; q < deg; ++q) {
        int slot = base + q;
        int s = min(g_srcB[slot], NN - 1);       // group-uniform
        const float* orow = cur + s * 16;
        float ej = g_ehsB[slot * 16 + j];        // coalesced 64B per group
        float4 o0 = *(const float4*)(orow + 0);  // broadcast
        float4 o1 = *(const float4*)(orow + 4);
        float4 o2 = *(const float4*)(orow + 8);
        float4 o3 = *(const float4*)(orow + 12);
        Gd[0]  += ej * o0.x; Gd[1]  += ej * o0.y; Gd[2]  += ej * o0.z; Gd[3]  += ej * o0.w;
        Gd[4]  += ej * o1.x; Gd[5]  += ej * o1.y; Gd[6]  += ej * o1.z; Gd[7]  += ej * o1.w;
        Gd[8]  += ej * o2.x; Gd[9]  += ej * o2.y; Gd[10] += ej * o2.z; Gd[11] += ej * o2.w;
        Gd[12] += ej * o3.x; Gd[13] += ej * o3.y; Gd[14] += ej * o3.z; Gd[15] += ej * o3.w;
        r16 += orow[j];
    }

    // ---- contraction: part[k'] via b128 s_W2 reads ----
    const float* wj = s_W2 + j * 276;
    float part[16];
#pragma unroll
    for (int kp = 0; kp < 16; ++kp) {
        const float* w = wj + kp * 16;
        float4 w0 = *(const float4*)(w + 0);
        float4 w1 = *(const float4*)(w + 4);
        float4 w2 = *(const float4*)(w + 8);
        float4 w3 = *(const float4*)(w + 12);
        part[kp] = Gd[0] * w0.x + Gd[1] * w0.y + Gd[2] * w0.z + Gd[3] * w0.w
                 + Gd[4] * w1.x + Gd[5] * w1.y + Gd[6] * w1.z + Gd[7] * w1.w
                 + Gd[8] * w2.x + Gd[9] * w2.y + Gd[10] * w2.z + Gd[11] * w2.w
                 + Gd[12] * w3.x + Gd[13] * w3.y + Gd[14] * w3.z + Gd[15] * w3.w;
    }
    {   // fold bias row: part[k'] += r16 * b2[j*16+k']
        float4 b0 = *(const float4*)(wj + 256);
        float4 b1 = *(const float4*)(wj + 260);
        float4 b2v = *(const float4*)(wj + 264);
        float4 b3 = *(const float4*)(wj + 268);
        part[0] += r16 * b0.x;  part[1] += r16 * b0.y;  part[2] += r16 * b0.z;  part[3] += r16 * b0.w;
        part[4] += r16 * b1.x;  part[5] += r16 * b1.y;  part[6] += r16 * b1.z;  part[7] += r16 * b1.w;
        part[8] += r16 * b2v.x; part[9] += r16 * b2v.y; part[10] += r16 * b2v.z; part[11] += r16 * b2v.w;
        part[12] += r16 * b3.x; part[13] += r16 * b3.y; part[14] += r16 * b3.z; part[15] += r16 * b3.w;
    }

    // ---- j-reduction: halving butterfly, 15 shfl_xor; lane j ends with a[j] --
    float w8[8];
#pragma unroll
    for (int i = 0; i < 8; ++i) {
        int keep = 2 * i + (j & 1);
        w8[i] = part[keep] + __shfl_xor(part[keep ^ 1], 1);
    }
    float w4[4];
#pragma unroll
    for (int i = 0; i < 4; ++i) {
        int keep = 2 * i + ((j >> 1) & 1);
        w4[i] = w8[keep] + __shfl_xor(w8[keep ^ 1], 2);
    }
    float w2[2];
#pragma unroll
    for (int i = 0; i < 2; ++i) {
        int keep = 2 * i + ((j >> 2) & 1);
        w2[i] = w4[keep] + __shfl_xor(w4[keep ^ 1], 4);
    }
    float aggr;
    {
        int keep = (j >> 3) & 1;
        aggr = w2[keep] + __shfl_xor(w2[keep ^ 1], 8);
    }
    float invd = 1.0f / (float)(deg > 0 ? deg : 1);
    float a_k = aggr * invd;
    const int k = j;

    // ---- node update: conv + GRU (b128 LDS weights) ----
    const float* nrow = cur + n * 16;
    float4 q0 = *(const float4*)(nrow + 0);
    float4 q1 = *(const float4*)(nrow + 4);
    float4 q2 = *(const float4*)(nrow + 8);
    float4 q3 = *(const float4*)(nrow + 12);
    float o[16] = {q0.x, q0.y, q0.z, q0.w, q1.x, q1.y, q1.z, q1.w,
                   q2.x, q2.y, q2.z, q2.w, q3.x, q3.y, q3.z, q3.w};
    float ok = o[k];

    float mcc = s_cb[k] + a_k;
    {
        const float* c = s_crT + k * 20;
        float4 c0 = *(const float4*)(c + 0);
        float4 c1 = *(const float4*)(c + 4);
        float4 c2 = *(const float4*)(c + 8);
        float4 c3 = *(const float4*)(c + 12);
        mcc += o[0] * c0.x + o[1] * c0.y + o[2] * c0.z + o[3] * c0.w
             + o[4] * c1.x + o[5] * c1.y + o[6] * c1.z + o[7] * c1.w
             + o[8] * c2.x + o[9] * c2.y + o[10] * c2.z + o[11] * c2.w
             + o[12] * c3.x + o[13] * c3.y + o[14] * c3.z + o[15] * c3.w;
    }
    float m = fmaxf(mcc, 0.0f);

    float md[16];
#pragma unroll
    for (int d = 0; d < 16; ++d) md[d] = __shfl(m, d, 16);

    float ir = s_bi[k], iz = s_bi[16 + k], in_ = s_bi[32 + k];
    float hr = s_bh[k], hz = s_bh[16 + k], hh = s_bh[32 + k];
#pragma unroll
    for (int g = 0; g < 3; ++g) {
        const float* wrow_i = s_wi + (g * 16 + k) * 20;
        const float* wrow_h = s_wh + (g * 16 + k) * 20;
        float acc_i = 0.0f, acc_h = 0.0f;
#pragma unroll
        for (int d4 = 0; d4 < 4; ++d4) {
            float4 wiv = *(const float4*)(wrow_i + d4 * 4);
            float4 whv = *(const float4*)(wrow_h + d4 * 4);
            acc_i += md[d4 * 4] * wiv.x + md[d4 * 4 + 1] * wiv.y
                   + md[d4 * 4 + 2] * wiv.z + md[d4 * 4 + 3] * wiv.w;
            acc_h += o[d4 * 4] * whv.x + o[d4 * 4 + 1] * whv.y
                   + o[d4 * 4 + 2] * whv.z + o[d4 * 4 + 3] * whv.w;
        }
        if (g == 0) { ir += acc_i; hr += acc_h; }
        else if (g == 1) { iz += acc_i; hz += acc_h; }
        else { in_ += acc_i; hh += acc_h; }
    }
    float rg = 1.0f / (1.0f + __expf(-(ir + hr)));
    float z  = 1.0f / (1.0f + __expf(-(iz + hz)));
    float nh = tanhf(in_ + rg * hh);
    float hnew = (1.0f - z) * nh + z * ok;

    if (last) out_final[n * 16 + k] = hnew;
    else      nxt[n * 16 + k] = hnew;
}

extern "C" void kernel_launch(void* const* d_in, const int* in_sizes, int n_in,
                              void* d_out, int out_size, void* d_ws, size_t ws_size,
                              hipStream_t stream) {
    const float* x         = (const float*)d_in[0];
    const int*   ei        = (const int*)d_in[1];
    const float* edge_attr = (const float*)d_in[2];
    const float* lin0_w    = (const float*)d_in[3];
    const float* lin0_b    = (const float*)d_in[4];
    const float* nn1_w     = (const float*)d_in[5];
    const float* nn1_b     = (const float*)d_in[6];
    const float* nn2_w     = (const float*)d_in[7];
    const float* nn2_b     = (const float*)d_in[8];
    const float* conv_root = (const float*)d_in[9];
    const float* conv_bias = (const float*)d_in[10];
    const float* gru_w_ih  = (const float*)d_in[11];
    const float* gru_w_hh  = (const float*)d_in[12];
    const float* gru_b_ih  = (const float*)d_in[13];
    const float* gru_b_hh  = (const float*)d_in[14];
    float* out = (float*)d_out;

    k_setup<<<NE / 256, 256, 0, stream>>>(ei, x, lin0_w, lin0_b,
                                          edge_attr, nn1_w, nn1_b);

    for (int r = 0; r < 6; ++r) {
        k_round<<<NN / 16, 256, 0, stream>>>(nn2_w, nn2_b, conv_root, conv_bias,
                                             gru_w_ih, gru_w_hh, gru_b_ih, gru_b_hh,
                                             out, r & 1, r == 5 ? 1 : 0);
    }
}